// Round 2
// baseline (19.668 us; speedup 1.0000x reference)
//
#include <hip/hip_runtime.h>
#include <hip/hip_bf16.h>

// Problem constants (from setup_inputs): B=16, T=512, D=384, F=1, M=4096, mel_max_len=1536
constexpr int B    = 16;
constexpr int T    = 512;   // durations per batch
constexpr int D    = 384;   // enc_out feature dim
constexpr int M    = 4096;  // pitch length
constexpr int MML  = 1536;  // mel_max_len
constexpr int V    = D / 4; // float4 per row = 96

constexpr int LCHUNK = 12;           // output rows per gather block
constexpr int CHUNKS = MML / LCHUNK; // 128

// Output layout (flat float32):
//   [0, B*MML*D)                 enc_rep
//   [B*MML*D, +B)                dec_lens (as float)
//   [+B, +B + B*T)               pitch_avg (F=1)
constexpr long ENC_SZ    = (long)B * MML * D;
constexpr long DEC_OFF   = ENC_SZ;
constexpr long PITCH_OFF = ENC_SZ + B;

typedef float f32x4 __attribute__((ext_vector_type(4)));

// ---------------- Kernel A: scan + tmap expansion (16 blocks) ----------------
// ws layout: tmap[B][MML] ints, then cums[B][T+1] ints.
__global__ __launch_bounds__(256)
void prep_kernel(const int* __restrict__ durs, int* __restrict__ tmap,
                 int* __restrict__ cums)
{
    const int b   = blockIdx.x;
    const int tid = threadIdx.x;
    const int lane = tid & 63, wid = tid >> 6;

    __shared__ int s_wsum[4];
    __shared__ int s_cums[T + 1];

    // pace == 1.0 => reps == durs exactly (int round-trip of d + 0.5)
    const int* db = durs + (size_t)b * T;
    const int d0 = db[2 * tid];
    const int d1 = db[2 * tid + 1];
    const int p  = d0 + d1;

    // wave-level inclusive scan of pair sums (6 shfl steps, no barriers)
    int inc = p;
    #pragma unroll
    for (int off = 1; off < 64; off <<= 1) {
        int n = __shfl_up(inc, off, 64);
        if (lane >= off) inc += n;
    }
    if (lane == 63) s_wsum[wid] = inc;
    __syncthreads();
    int woff = 0;
    #pragma unroll
    for (int w = 0; w < 4; ++w) woff += (w < wid) ? s_wsum[w] : 0;

    const int e = woff + inc - p;        // exclusive prefix of this pair
    s_cums[2 * tid]     = e;
    s_cums[2 * tid + 1] = e + d0;
    if (tid == 255) s_cums[T] = e + p;   // total
    __syncthreads();

    // persist cums for the gather kernel's pitch pass
    int* cb = cums + b * (T + 1);
    for (int i = tid; i < T + 1; i += 256) cb[i] = s_cums[i];

    // expand frame map: tmap[l] = t  for  cums[t] <= l < cums[t+1], l < MML
    const int total = s_cums[T];
    int* tb = tmap + b * MML;
    for (int t = tid; t < T; t += 256) {
        int s  = s_cums[t];
        int en = s_cums[t + 1];
        if (en > MML) en = MML;
        for (int k = s; k < en; ++k) tb[k] = t;
    }
    const int lim = total < MML ? total : MML;
    for (int k = lim + tid; k < MML; k += 256) tb[k] = -1;
}

// ---------------- Kernel B: streaming gather + pitch/dec ----------------
__global__ __launch_bounds__(256)
void gather_kernel(const float* __restrict__ enc,
                   const float* __restrict__ pitch,
                   const int*   __restrict__ tmap,
                   const int*   __restrict__ cums,
                   float*       __restrict__ out)
{
    const int tid = threadIdx.x;
    const int b   = blockIdx.y;
    const int cx  = blockIdx.x;

    __shared__ int s_t[LCHUNK];
    __shared__ int s_c[T + 1];

    // x==0 column: pitch averages + dec_lens FIRST (overlaps others' copy)
    if (cx == 0) {
        const int* cb = cums + b * (T + 1);
        for (int i = tid; i < T + 1; i += 256) s_c[i] = cb[i];
        __syncthreads();
        if (tid == 0) {
            int total = s_c[T];
            out[DEC_OFF + b] = (float)(total < MML ? total : MML);
        }
        const float* pb = pitch + (size_t)b * M;   // F == 1, ends <= 3584 < M
        for (int l = tid; l < T; l += 256) {
            int s  = s_c[l];
            int en = s_c[l + 1];
            float sum = 0.f;
            int   cnt = 0;
            for (int k = s; k < en; ++k) {
                float v = pb[k];
                sum += v;
                cnt += (v != 0.0f);
            }
            out[PITCH_OFF + (size_t)b * T + l] = cnt ? sum / (float)cnt : 0.0f;
        }
        __syncthreads();
    }

    // row copy: 12 rows x 96 float4, fully coalesced, nontemporal stores
    const int l0 = cx * LCHUNK;
    if (tid < LCHUNK) s_t[tid] = tmap[b * MML + l0 + tid];
    __syncthreads();

    const f32x4* src = (const f32x4*)(enc + (size_t)b * T * D);
    f32x4*       dst = (f32x4*)(out + ((size_t)b * MML + l0) * D);

    #pragma unroll
    for (int k = 0; k < 5; ++k) {        // ceil(1152/256) = 5 (last partial)
        int idx = tid + k * 256;
        if (idx < LCHUNK * V) {
            int ll = idx / V;
            int j  = idx - ll * V;
            int t  = s_t[ll];
            f32x4 v;
            if (t >= 0) v = src[(size_t)t * V + j];
            else        v = (f32x4)(0.0f);
            __builtin_nontemporal_store(v, &dst[(size_t)ll * V + j]);
        }
    }
}

extern "C" void kernel_launch(void* const* d_in, const int* in_sizes, int n_in,
                              void* d_out, int out_size, void* d_ws, size_t ws_size,
                              hipStream_t stream) {
    const float* enc   = (const float*)d_in[0];
    const int*   durs  = (const int*)d_in[1];
    const float* pitch = (const float*)d_in[2];
    float*       out   = (float*)d_out;

    int* tmap = (int*)d_ws;            // B*MML ints = 98304 B
    int* cums = tmap + B * MML;        // B*(T+1) ints = 32832 B

    prep_kernel<<<B, 256, 0, stream>>>(durs, tmap, cums);
    gather_kernel<<<dim3(CHUNKS, B), 256, 0, stream>>>(enc, pitch, tmap, cums, out);
}

// Round 3
// 14.397 us; speedup vs baseline: 1.3661x; 1.3661x over previous
//
#include <hip/hip_runtime.h>
#include <hip/hip_bf16.h>

// Problem constants: B=16, T=512, D=384, F=1, M=4096, mel_max_len=1536
constexpr int B    = 16;
constexpr int T    = 512;
constexpr int D    = 384;
constexpr int M    = 4096;
constexpr int MML  = 1536;
constexpr int V    = D / 4;          // 96 float4 per row

constexpr int LCHUNK = 12;           // output rows per block
constexpr int CHUNKS = MML / LCHUNK; // 128
constexpr int PROWS  = 4;            // pitch rows per block (128*4 = 512 = T)

// Output layout (flat float32): enc_rep | dec_lens | pitch_avg
constexpr long ENC_SZ    = (long)B * MML * D;
constexpr long DEC_OFF   = ENC_SZ;
constexpr long PITCH_OFF = ENC_SZ + B;

typedef float f32x4 __attribute__((ext_vector_type(4)));

__global__ __launch_bounds__(256)
void fastpitch_fused(const float* __restrict__ enc,     // (B,T,D)
                     const int*   __restrict__ durs,    // (B,T)
                     const float* __restrict__ pitch,   // (B,1,M)
                     float*       __restrict__ out)
{
    __shared__ int s_cums[T + 1];
    __shared__ int s_t[LCHUNK];

    const int tid = threadIdx.x;
    const int b   = blockIdx.y;
    const int cx  = blockIdx.x;

    // ---- 1. duration cumsum: single-wave shfl scan (pace==1 => reps==durs) ----
    if (tid < 64) {
        const int4* db = (const int4*)(durs + (size_t)b * T);
        int4 a = db[2 * tid];
        int4 c = db[2 * tid + 1];
        int p0 = a.x;
        int p1 = p0 + a.y;
        int p2 = p1 + a.z;
        int p3 = p2 + a.w;
        int p4 = p3 + c.x;
        int p5 = p4 + c.y;
        int p6 = p5 + c.z;
        int p7 = p6 + c.w;          // lane sum
        int inc = p7;
        #pragma unroll
        for (int off = 1; off < 64; off <<= 1) {
            int n = __shfl_up(inc, off, 64);
            if (tid >= off) inc += n;
        }
        const int excl = inc - p7;  // exclusive lane prefix
        const int base = 8 * tid;
        s_cums[base + 1] = excl + p0;
        s_cums[base + 2] = excl + p1;
        s_cums[base + 3] = excl + p2;
        s_cums[base + 4] = excl + p3;
        s_cums[base + 5] = excl + p4;
        s_cums[base + 6] = excl + p5;
        s_cums[base + 7] = excl + p6;
        s_cums[base + 8] = excl + p7;
        if (tid == 0) s_cums[0] = 0;
    }
    __syncthreads();

    // ---- 2. frame index for this block's 12 rows (binary search) ----
    if (tid < LCHUNK) {
        const int l = cx * LCHUNK + tid;
        int lo = 0, hi = T;
        while (lo < hi) {
            int mid = (lo + hi + 1) >> 1;
            if (s_cums[mid] <= l) lo = mid; else hi = mid - 1;
        }
        s_t[tid] = (lo < T) ? lo : -1;   // lo==T <=> l >= total
    }
    __syncthreads();

    // ---- 3. row copy: 12 x 96 float4, coalesced, nontemporal stores ----
    {
        const f32x4* src = (const f32x4*)(enc + (size_t)b * T * D);
        f32x4*       dst = (f32x4*)(out + ((size_t)b * MML + cx * LCHUNK) * D);
        #pragma unroll
        for (int k = 0; k < 5; ++k) {    // ceil(1152/256)=5, last partial
            int idx = tid + k * 256;
            if (idx < LCHUNK * V) {
                int ll = idx / V;
                int j  = idx - ll * V;
                int t  = s_t[ll];
                f32x4 v;
                if (t >= 0) v = src[(size_t)t * V + j];
                else        v = (f32x4)(0.0f);
                __builtin_nontemporal_store(v, &dst[(size_t)ll * V + j]);
            }
        }
    }

    // ---- 4. pitch averages: 4 rows per block, spread over whole grid ----
    if (tid < PROWS) {
        const int r = cx * PROWS + tid;          // 0..511
        const int s  = s_cums[r];
        const int en = s_cums[r + 1];            // <= total <= 3584 < M
        const float* pb = pitch + (size_t)b * M; // F == 1
        float sum = 0.f;
        int   cnt = 0;
        for (int k = s; k < en; ++k) {           // at most 7 iterations
            float v = pb[k];
            sum += v;
            cnt += (v != 0.0f);
        }
        out[PITCH_OFF + (size_t)b * T + r] = cnt ? sum / (float)cnt : 0.0f;
    }

    // ---- 5. dec_lens ----
    if (cx == 0 && tid == 0) {
        const int total = s_cums[T];
        out[DEC_OFF + b] = (float)(total < MML ? total : MML);
    }
}

extern "C" void kernel_launch(void* const* d_in, const int* in_sizes, int n_in,
                              void* d_out, int out_size, void* d_ws, size_t ws_size,
                              hipStream_t stream) {
    const float* enc   = (const float*)d_in[0];
    const int*   durs  = (const int*)d_in[1];
    const float* pitch = (const float*)d_in[2];
    float*       out   = (float*)d_out;

    fastpitch_fused<<<dim3(CHUNKS, B), 256, 0, stream>>>(enc, durs, pitch, out);
}

// Round 4
// 13.958 us; speedup vs baseline: 1.4091x; 1.0315x over previous
//
#include <hip/hip_runtime.h>
#include <hip/hip_bf16.h>

// Problem constants: B=16, T=512, D=384, F=1, M=4096, mel_max_len=1536
constexpr int B    = 16;
constexpr int T    = 512;
constexpr int D    = 384;
constexpr int M    = 4096;
constexpr int MML  = 1536;
constexpr int V    = D / 4;          // 96 float4 per row

constexpr int LCHUNK = 16;           // output rows per block -> 16*96 = 1536 = 6*256 exact
constexpr int CHUNKS = MML / LCHUNK; // 96

// Output layout (flat float32): enc_rep | dec_lens | pitch_avg
constexpr long ENC_SZ    = (long)B * MML * D;
constexpr long DEC_OFF   = ENC_SZ;
constexpr long PITCH_OFF = ENC_SZ + B;

typedef float f32x4 __attribute__((ext_vector_type(4)));

__global__ __launch_bounds__(256)
void fastpitch_fused(const float* __restrict__ enc,     // (B,T,D)
                     const int*   __restrict__ durs,    // (B,T)
                     const float* __restrict__ pitch,   // (B,1,M)
                     float*       __restrict__ out)
{
    __shared__ int s_cums[T + 1];
    __shared__ int s_t[LCHUNK];

    const int tid = threadIdx.x;
    const int b   = blockIdx.y;
    const int cx  = blockIdx.x;

    // ---- 1. duration cumsum: single-wave shfl scan (pace==1 => reps==durs) ----
    if (tid < 64) {
        const int4* db = (const int4*)(durs + (size_t)b * T);
        int4 a = db[2 * tid];
        int4 c = db[2 * tid + 1];
        int p0 = a.x;
        int p1 = p0 + a.y;
        int p2 = p1 + a.z;
        int p3 = p2 + a.w;
        int p4 = p3 + c.x;
        int p5 = p4 + c.y;
        int p6 = p5 + c.z;
        int p7 = p6 + c.w;          // lane sum
        int inc = p7;
        #pragma unroll
        for (int off = 1; off < 64; off <<= 1) {
            int n = __shfl_up(inc, off, 64);
            if (tid >= off) inc += n;
        }
        const int excl = inc - p7;
        const int base = 8 * tid;
        s_cums[base + 1] = excl + p0;
        s_cums[base + 2] = excl + p1;
        s_cums[base + 3] = excl + p2;
        s_cums[base + 4] = excl + p3;
        s_cums[base + 5] = excl + p4;
        s_cums[base + 6] = excl + p5;
        s_cums[base + 7] = excl + p6;
        s_cums[base + 8] = excl + p7;
        if (tid == 0) s_cums[0] = 0;
    }
    __syncthreads();   // B1: s_cums ready

    // ---- 2a. frame index for this block's 16 rows (lanes 0..15 of wave 0) ----
    if (tid < LCHUNK) {
        const int l = cx * LCHUNK + tid;
        int lo = 0, hi = T;
        while (lo < hi) {
            int mid = (lo + hi + 1) >> 1;
            if (s_cums[mid] <= l) lo = mid; else hi = mid - 1;
        }
        s_t[tid] = (lo < T) ? lo : -1;   // lo==T <=> l >= total
    }

    // ---- 2b. pitch: issue masked parallel loads on lanes 16..63 (6 rows x 8 lanes)
    //          (latency hides under the search + row copy; reduce happens after)
    float p_val = 0.f;
    int   p_nz  = 0;
    int   p_row = -1;
    if (tid >= 16 && tid < 64) {
        const int g = tid - 16;
        const int i = g >> 3;                 // 0..5
        const int j = g & 7;                  // 0..7
        const int r = cx + CHUNKS * i;        // strided rows, 96*6=576 covers 512
        if (r < T) {
            p_row = r;
            const int s  = s_cums[r];
            const int en = s_cums[r + 1];     // en - s <= 7
            if (j < en - s) {
                const float v = pitch[(size_t)b * M + s + j];
                p_val = v;
                p_nz  = (v != 0.0f);
            }
        }
    }

    // ---- 2c. dec_lens on an otherwise-idle wave-1 lane ----
    if (cx == 0 && tid == 64) {
        const int total = s_cums[T];
        out[DEC_OFF + b] = (float)(total < MML ? total : MML);
    }
    __syncthreads();   // B2: s_t ready

    // ---- 3. row copy: 16 x 96 float4 = 6 full-lane iterations, NT stores ----
    {
        const f32x4* src = (const f32x4*)(enc + (size_t)b * T * D);
        f32x4*       dst = (f32x4*)(out + ((size_t)b * MML + cx * LCHUNK) * D);
        #pragma unroll
        for (int k = 0; k < 6; ++k) {
            const int idx = tid + k * 256;    // < 1536 always
            const int ll  = idx / V;
            const int j   = idx - ll * V;
            const int t   = s_t[ll];
            f32x4 v;
            if (t >= 0) v = src[(size_t)t * V + j];
            else        v = (f32x4)(0.0f);
            __builtin_nontemporal_store(v, &dst[(size_t)ll * V + j]);
        }
    }

    // ---- 4. pitch reduce (8-lane groups within wave 0) + store ----
    if (p_row >= 0 || (tid >= 16 && tid < 64)) {
        float sum = p_val;
        int   cnt = p_nz;
        #pragma unroll
        for (int m = 1; m < 8; m <<= 1) {
            sum += __shfl_xor(sum, m, 64);
            cnt += __shfl_xor(cnt, m, 64);
        }
        if (((tid - 16) & 7) == 0 && p_row >= 0) {
            out[PITCH_OFF + (size_t)b * T + p_row] = cnt ? sum / (float)cnt : 0.0f;
        }
    }
}

extern "C" void kernel_launch(void* const* d_in, const int* in_sizes, int n_in,
                              void* d_out, int out_size, void* d_ws, size_t ws_size,
                              hipStream_t stream) {
    const float* enc   = (const float*)d_in[0];
    const int*   durs  = (const int*)d_in[1];
    const float* pitch = (const float*)d_in[2];
    float*       out   = (float*)d_out;

    fastpitch_fused<<<dim3(CHUNKS, B), 256, 0, stream>>>(enc, durs, pitch, out);
}

// Round 5
// 13.634 us; speedup vs baseline: 1.4426x; 1.0238x over previous
//
#include <hip/hip_runtime.h>
#include <hip/hip_bf16.h>

// Problem constants: B=16, T=512, D=384, F=1, M=4096, mel_max_len=1536
constexpr int B    = 16;
constexpr int T    = 512;
constexpr int D    = 384;
constexpr int M    = 4096;
constexpr int MML  = 1536;
constexpr int V    = D / 4;          // 96 float4 per row

constexpr int LCHUNK = 32;           // rows per block -> 32*96 = 3072 = 12*256 exact
constexpr int CHUNKS = MML / LCHUNK; // 48
constexpr int PR     = 16;           // pitch rows per block (48*16 = 768 >= 512)

// Output layout (flat float32): enc_rep | dec_lens | pitch_avg
constexpr long ENC_SZ    = (long)B * MML * D;
constexpr long DEC_OFF   = ENC_SZ;
constexpr long PITCH_OFF = ENC_SZ + B;

typedef float f32x4 __attribute__((ext_vector_type(4)));

__global__ __launch_bounds__(256)
void fastpitch_fused(const float* __restrict__ enc,     // (B,T,D)
                     const int*   __restrict__ durs,    // (B,T)
                     const float* __restrict__ pitch,   // (B,1,M)
                     float*       __restrict__ out)
{
    __shared__ int s_cums[T + 1];
    __shared__ int s_t[LCHUNK];

    const int tid = threadIdx.x;
    const int b   = blockIdx.y;
    const int cx  = blockIdx.x;

    // ---- 1. duration cumsum: single-wave shfl scan (pace==1 => reps==durs) ----
    if (tid < 64) {
        const int4* db = (const int4*)(durs + (size_t)b * T);
        int4 a = db[2 * tid];
        int4 c = db[2 * tid + 1];
        int p0 = a.x;
        int p1 = p0 + a.y;
        int p2 = p1 + a.z;
        int p3 = p2 + a.w;
        int p4 = p3 + c.x;
        int p5 = p4 + c.y;
        int p6 = p5 + c.z;
        int p7 = p6 + c.w;          // lane sum
        int inc = p7;
        #pragma unroll
        for (int off = 1; off < 64; off <<= 1) {
            int n = __shfl_up(inc, off, 64);
            if (tid >= off) inc += n;
        }
        const int excl = inc - p7;
        const int base = 8 * tid;
        s_cums[base + 1] = excl + p0;
        s_cums[base + 2] = excl + p1;
        s_cums[base + 3] = excl + p2;
        s_cums[base + 4] = excl + p3;
        s_cums[base + 5] = excl + p4;
        s_cums[base + 6] = excl + p5;
        s_cums[base + 7] = excl + p6;
        s_cums[base + 8] = excl + p7;
        if (tid == 0) s_cums[0] = 0;
    }
    __syncthreads();   // B1: s_cums ready

    // ---- 2a. frame index for this block's 32 rows (lanes 0..31 of wave 0) ----
    if (tid < LCHUNK) {
        const int l = cx * LCHUNK + tid;
        int lo = 0, hi = T;
        while (lo < hi) {
            int mid = (lo + hi + 1) >> 1;
            if (s_cums[mid] <= l) lo = mid; else hi = mid - 1;
        }
        s_t[tid] = (lo < T) ? lo : -1;   // lo==T <=> l >= total
    }

    // ---- 2b. pitch: masked parallel loads on waves 1-2 (16 rows x 8 lanes);
    //          loads issue here, latency hides under the row copy ----
    float p_val = 0.f;
    int   p_nz  = 0;
    int   p_row = -1;
    if (tid >= 64 && tid < 192) {
        const int g = tid - 64;
        const int i = g >> 3;                 // 0..15
        const int j = g & 7;                  // 0..7
        const int r = cx + CHUNKS * i;        // bijection onto [0,768)
        if (r < T) {
            p_row = r;
            const int s  = s_cums[r];
            const int en = s_cums[r + 1];     // en - s <= 7
            if (j < en - s) {
                const float v = pitch[(size_t)b * M + s + j];
                p_val = v;
                p_nz  = (v != 0.0f);
            }
        }
    }

    // ---- 2c. dec_lens on an idle wave-3 lane ----
    if (cx == 0 && tid == 192) {
        const int total = s_cums[T];
        out[DEC_OFF + b] = (float)(total < MML ? total : MML);
    }
    __syncthreads();   // B2: s_t ready

    // ---- 3. row copy: 32 x 96 float4 = 12 exact full-lane iterations, NT stores ----
    {
        const f32x4* src = (const f32x4*)(enc + (size_t)b * T * D);
        f32x4*       dst = (f32x4*)(out + ((size_t)b * MML + cx * LCHUNK) * D);
        #pragma unroll
        for (int k = 0; k < 12; ++k) {
            const int idx = tid + k * 256;    // < 3072 always
            const int ll  = idx / V;
            const int j   = idx - ll * V;
            const int t   = s_t[ll];
            f32x4 v;
            if (t >= 0) v = src[(size_t)t * V + j];
            else        v = (f32x4)(0.0f);
            __builtin_nontemporal_store(v, &dst[(size_t)ll * V + j]);
        }
    }

    // ---- 4. pitch reduce (8-lane groups within waves 1-2) + store ----
    if (tid >= 64 && tid < 192) {
        float sum = p_val;
        int   cnt = p_nz;
        #pragma unroll
        for (int m = 1; m < 8; m <<= 1) {
            sum += __shfl_xor(sum, m, 64);
            cnt += __shfl_xor(cnt, m, 64);
        }
        if (((tid - 64) & 7) == 0 && p_row >= 0) {
            out[PITCH_OFF + (size_t)b * T + p_row] = cnt ? sum / (float)cnt : 0.0f;
        }
    }
}

extern "C" void kernel_launch(void* const* d_in, const int* in_sizes, int n_in,
                              void* d_out, int out_size, void* d_ws, size_t ws_size,
                              hipStream_t stream) {
    const float* enc   = (const float*)d_in[0];
    const int*   durs  = (const int*)d_in[1];
    const float* pitch = (const float*)d_in[2];
    float*       out   = (float*)d_out;

    fastpitch_fused<<<dim3(CHUNKS, B), 256, 0, stream>>>(enc, durs, pitch, out);
}